// Round 1
// baseline (954.776 us; speedup 1.0000x reference)
//
#include <hip/hip_runtime.h>
#include <math.h>

#define STEPS  20000
#define NS     2048
#define NBINS  200000
#define SEGLEN 80                 // steps per segment
#define NSEG   250                // STEPS/SEGLEN
#define NT     512000             // NSEG*NS segment-threads (layout unit)
#define NT4    128000             // NSEG*(NS/4) quad-column threads
#define WPS    5                  // 16-step words per segment

typedef float        f32x4 __attribute__((ext_vector_type(4)));
typedef unsigned int u32x4 __attribute__((ext_vector_type(4)));

// ---- CDF constants for state-1 row, computed exactly as numpy does ----
constexpr double S1d = 5e7 + 3e6 + 2e4 + 7e7;      // 123020000, exact
constexpr double P0d = 5e7 / S1d;
constexpr double P2d = 3e6 / S1d;
constexpr double P3d = 2e4 / S1d;
constexpr float C0 = (float)(P0d);                  // cdf[0] == cdf[1]
constexpr float C2 = (float)(P0d + P2d);            // cdf[2]
constexpr float C3 = (float)((P0d + P2d) + P3d);    // cdf[3]

constexpr float INV_R0 = 1.0f / 1e6f;
constexpr float INV_R1 = 1.0f / 123020000.0f;
constexpr float INV_R2 = 1.0f / 1e5f;
constexpr float INV_R3 = 5.0f;                      // 1/0.2

// ---- workspace layout (bytes); total 23,552,004 ----
#define WS_T1P   0u          // u32 [WPS][NT]  10,240,000
#define WS_MAPS  10240000u   // u8  [NT]          512,000
#define WS_PCNT4 10752000u   // u32 [NT]        2,048,000
#define WS_SUMS4 12800000u   // f4  [NT]        8,192,000
#define WS_ENTER 20992000u   // u8  [NT]          512,000
#define WS_OFFS  21504000u   // f32 [NT]        2,048,000
#define WS_PTOT  23552000u   // int

__device__ __forceinline__ int te_decode(float u1) {
    return (u1 < C2) ? ((u1 < C0) ? 0 : 2) : ((u1 < C3) ? 3 : 0);
}
__device__ __forceinline__ int next_state(int s, int te) {
    return (s == 0) ? 1 : ((s == 1) ? te : 0);
}
__device__ __forceinline__ float inv_of(int s) {
    return (s == 0) ? INV_R0 : ((s == 1) ? INV_R1 : ((s == 2) ? INV_R2 : INV_R3));
}
__device__ __forceinline__ float dwell_base(float ue) {
    return -__logf(1.0f - ue);      // == -log1p(-ue), cheap (v_log_f32)
}

// searchsorted(bins, v, 'left'), bins[i]=float(i)*0.002f. Branchless: guess
// is within +-2 of truth, walk-up fixed 4 steps, clamp to NBINS.
__device__ __forceinline__ int bucketize(float v) {
    int lo = (int)(v * 500.0f) - 2;
    lo = lo < 0 ? 0 : lo;
#pragma unroll
    for (int i = 0; i < 4; ++i) lo += ((float)lo * 0.002f < v) ? 1 : 0;
    return lo > NBINS ? NBINS : lo;
}

__global__ void zero_kernel(float* __restrict__ hist, int* __restrict__ ptot) {
    int i = blockIdx.x * blockDim.x + threadIdx.x;
    if (i <= NBINS) hist[i] = 0.0f;
    if (i == 0) *ptot = 0;
}

// K1: per-segment transition maps, packed te stream, photon counts and dwell
// sums for all 4 possible entering states. 4 adjacent columns per thread so
// every global access is 16B/lane (f32x4 / u32x4).
__global__ void __launch_bounds__(256)
map_dwell_kernel(const float* __restrict__ u_cat, const float* __restrict__ u_exp,
                 unsigned int* __restrict__ t1p, unsigned char* __restrict__ maps,
                 unsigned int* __restrict__ pcnt4, float4* __restrict__ sums4)
{
    const int q = blockIdx.x * 256 + threadIdx.x;       // 0..NT4-1
    const int seg  = q >> 9;                            // 0..249
    const int colq = q & 511;                           // quad-column index
    const int tbase = seg * NS + colq * 4;              // base t-index of 4 cols
    const size_t f4b = (size_t)seg * SEGLEN * (NS / 4) + colq;
    const f32x4* uc4 = (const f32x4*)u_cat + f4b;
    const f32x4* ue4 = (const f32x4*)u_exp + f4b;       // cached: K3 re-reads via L3

    f32x4 uc[2][4], ue[2][4];
#pragma unroll
    for (int j = 0; j < 4; ++j) {
        uc[0][j] = __builtin_nontemporal_load(uc4 + (size_t)j * (NS / 4));
        ue[0][j] = ue4[(size_t)j * (NS / 4)];
    }
    int st[4][4], n[4][4];
    float s[4][4];
#pragma unroll
    for (int c = 0; c < 4; ++c)
#pragma unroll
        for (int e = 0; e < 4; ++e) { st[c][e] = e; n[c][e] = 0; s[c][e] = 0.0f; }
    unsigned int wc[4] = {0u, 0u, 0u, 0u};

#pragma unroll
    for (int ch = 0; ch < 20; ++ch) {                   // 20 chunks x 4 steps
        const int cur = ch & 1, nxt = cur ^ 1;
        if (ch < 19) {
            const size_t rb = (size_t)(ch + 1) * 4 * (NS / 4);
#pragma unroll
            for (int j = 0; j < 4; ++j) {
                uc[nxt][j] = __builtin_nontemporal_load(uc4 + rb + (size_t)j * (NS / 4));
                ue[nxt][j] = ue4[rb + (size_t)j * (NS / 4)];
            }
        }
#pragma unroll
        for (int j = 0; j < 4; ++j) {
            const int sidx = ch * 4 + j;
#pragma unroll
            for (int c = 0; c < 4; ++c) {
                const int te = te_decode(uc[cur][j][c]);
                wc[c] |= (unsigned int)te << (2 * (sidx & 15));
                const float b = dwell_base(ue[cur][j][c]);
#pragma unroll
                for (int e = 0; e < 4; ++e) {
                    n[c][e] += (st[c][e] == 0);
                    s[c][e] += b * inv_of(st[c][e]);
                    st[c][e] = next_state(st[c][e], te);
                }
            }
        }
        if ((ch & 3) == 3) {                            // every 16 steps
            u32x4 wv = {wc[0], wc[1], wc[2], wc[3]};
            *(u32x4*)(t1p + (size_t)(ch >> 2) * NT + tbase) = wv;
            wc[0] = wc[1] = wc[2] = wc[3] = 0u;
        }
    }
    unsigned int m32 = 0;
#pragma unroll
    for (int c = 0; c < 4; ++c)
        m32 |= (unsigned int)(st[c][0] | (st[c][1] << 2) | (st[c][2] << 4) | (st[c][3] << 6)) << (8 * c);
    *(unsigned int*)(maps + tbase) = m32;
    u32x4 pv;
#pragma unroll
    for (int c = 0; c < 4; ++c)
        pv[c] = (unsigned int)(n[c][0] | (n[c][1] << 8) | (n[c][2] << 16) | (n[c][3] << 24));
    *(u32x4*)(pcnt4 + tbase) = pv;
#pragma unroll
    for (int c = 0; c < 4; ++c)
        sums4[tbase + c] = make_float4(s[c][0], s[c][1], s[c][2], s[c][3]);
}

// K2: per-column scan over 250 segments: entering state, entering time,
// and exact total photon count (block-reduced, 8 atomics total).
__global__ void __launch_bounds__(256)
scan_kernel(const unsigned char* __restrict__ maps, const unsigned int* __restrict__ pcnt4,
            const float4* __restrict__ sums4, unsigned char* __restrict__ enter,
            float* __restrict__ offs, int* __restrict__ ptot)
{
    const int col = blockIdx.x * 256 + threadIdx.x;   // 0..2047
    int state = 0, P = 0;
    float off = 0.0f;

    unsigned char mpA[5], mpB[5];
    unsigned int  mtA[5], mtB[5];
    float4        s4A[5], s4B[5];
#pragma unroll
    for (int j = 0; j < 5; ++j) {
        const int idx = j * NS + col;
        mpA[j] = maps[idx]; mtA[j] = pcnt4[idx]; s4A[j] = sums4[idx];
    }
#define SCAN_PREFETCH(BUFm, BUFt, BUFs, B)                                   \
    {   const int gb = (B) * 5;                                              \
        _Pragma("unroll")                                                    \
        for (int j = 0; j < 5; ++j) {                                        \
            const int idx = (gb + j) * NS + col;                             \
            BUFm[j] = maps[idx]; BUFt[j] = pcnt4[idx]; BUFs[j] = sums4[idx]; \
        } }
#define SCAN_PROCESS(BUFm, BUFt, BUFs, B)                                    \
    {   const int gb = (B) * 5;                                              \
        _Pragma("unroll")                                                    \
        for (int j = 0; j < 5; ++j) {                                        \
            const int idx = (gb + j) * NS + col;                             \
            enter[idx] = (unsigned char)state;                               \
            offs[idx]  = off;                                                \
            const float4 s = BUFs[j];                                        \
            const float lo = (state & 1) ? s.y : s.x;                        \
            const float hi = (state & 1) ? s.w : s.z;                        \
            off += (state & 2) ? hi : lo;                                    \
            P += (int)((BUFt[j] >> (8 * state)) & 0xffu);                    \
            state = (int)((BUFm[j] >> (2 * state)) & 3u);                    \
        } }
    for (int b = 0; b < 50; b += 2) {
        SCAN_PREFETCH(mpB, mtB, s4B, b + 1)
        SCAN_PROCESS(mpA, mtA, s4A, b)
        if (b + 2 < 50) SCAN_PREFETCH(mpA, mtA, s4A, b + 2)
        SCAN_PROCESS(mpB, mtB, s4B, b + 1)
    }
#undef SCAN_PREFETCH
#undef SCAN_PROCESS

    __shared__ int red[256];
    red[threadIdx.x] = P;
    __syncthreads();
#pragma unroll
    for (int s = 128; s > 0; s >>= 1) {
        if (threadIdx.x < s) red[threadIdx.x] += red[threadIdx.x + s];
        __syncthreads();
    }
    if (threadIdx.x == 0) atomicAdd(ptot, red[0]);
}

// hist[0] = total entries - total photons (exact).
__global__ void hist0_kernel(float* __restrict__ hist, const int* __restrict__ ptot) {
    if (threadIdx.x == 0 && blockIdx.x == 0)
        hist[0] = (float)(40960000 - *ptot);
}

// Wave-aggregated histogram flush: one atomic per distinct bin per wave.
// Must be called with all 64 lanes converged.
__device__ __forceinline__ void wave_flush(float* __restrict__ hist, int v, float cnt) {
    unsigned long long active = __ballot(v > 0);
    while (active) {
        const int leader = __ffsll((long long)active) - 1;
        const int vl = __shfl(v, leader, 64);
        const unsigned long long match = __ballot(v == vl);
        float c = (v == vl) ? cnt : 0.0f;
#pragma unroll
        for (int o = 32; o > 0; o >>= 1) c += __shfl_xor(c, o, 64);
        if ((int)(threadIdx.x & 63) == leader) atomicAdd(hist + vl, c);
        active &= ~match;
    }
}

// K3: final replay — photons, cum_time, histogram. 4 columns per thread:
// f32x4 loads of u_exp, f32x4 nontemporal stores of photons/cumt.
__global__ void __launch_bounds__(256)
final_kernel(const float* __restrict__ u_exp, const unsigned int* __restrict__ t1p,
             const unsigned char* __restrict__ enter, const float* __restrict__ offs,
             float* __restrict__ photons, float* __restrict__ cumt,
             float* __restrict__ hist)
{
    const int q = blockIdx.x * 256 + threadIdx.x;       // 0..NT4-1
    const int seg  = q >> 9;
    const int colq = q & 511;
    const int tbase = seg * NS + colq * 4;
    const size_t f4b = (size_t)seg * SEGLEN * (NS / 4) + colq;
    const f32x4* pe = (const f32x4*)u_exp + f4b;
    f32x4* pph = (f32x4*)photons + f4b;
    f32x4* pcm = (f32x4*)cumt + f4b;

    u32x4 w[WPS];
#pragma unroll
    for (int k = 0; k < WPS; ++k) w[k] = *(const u32x4*)(t1p + (size_t)k * NT + tbase);

    const unsigned int e4 = *(const unsigned int*)(enter + tbase);
    const f32x4 of4 = *(const f32x4*)(offs + tbase);
    int st[4];
    float cum[4];
#pragma unroll
    for (int c = 0; c < 4; ++c) { st[c] = (int)((e4 >> (8 * c)) & 3u); cum[c] = of4[c]; }

    int   v0[4] = {0, 0, 0, 0}, v1[4] = {0, 0, 0, 0};
    float r0[4] = {0, 0, 0, 0}, r1[4] = {0, 0, 0, 0};

    f32x4 ue[2][4];
#pragma unroll
    for (int j = 0; j < 4; ++j) ue[0][j] = pe[(size_t)j * (NS / 4)];

#pragma unroll
    for (int ch = 0; ch < 20; ++ch) {                   // 20 chunks x 4 steps
        const int cur = ch & 1, nxt = cur ^ 1;
        if (ch < 19) {
            const size_t rb = (size_t)(ch + 1) * 4 * (NS / 4);
#pragma unroll
            for (int j = 0; j < 4; ++j) ue[nxt][j] = pe[rb + (size_t)j * (NS / 4)];
        }
#pragma unroll
        for (int j = 0; j < 4; ++j) {
            const int sidx = ch * 4 + j;
            f32x4 phv, cmv;
#pragma unroll
            for (int c = 0; c < 4; ++c) {
                cum[c] += dwell_base(ue[cur][j][c]) * inv_of(st[c]);
                const bool ph = (st[c] == 0);
                phv[c] = ph ? 1.0f : 0.0f;
                cmv[c] = cum[c];
                if (ph) {
                    const int v = bucketize(cum[c]);
                    if (v == v0[c])       r0[c] += 1.0f;
                    else if (v == v1[c])  r1[c] += 1.0f;
                    else if (v0[c] == 0) { v0[c] = v; r0[c] = 1.0f; }
                    else if (v1[c] == 0) { v1[c] = v; r1[c] = 1.0f; }
                    else atomicAdd(hist + v, 1.0f);     // 3rd distinct bin: rare
                }
                st[c] = next_state(st[c], (int)((w[sidx >> 4][c] >> (2 * (sidx & 15))) & 3u));
            }
            __builtin_nontemporal_store(phv, pph + (size_t)sidx * (NS / 4));
            __builtin_nontemporal_store(cmv, pcm + (size_t)sidx * (NS / 4));
        }
    }
#pragma unroll
    for (int c = 0; c < 4; ++c) { wave_flush(hist, v0[c], r0[c]); wave_flush(hist, v1[c], r1[c]); }
}

extern "C" void kernel_launch(void* const* d_in, const int* in_sizes, int n_in,
                              void* d_out, int out_size, void* d_ws, size_t ws_size,
                              hipStream_t stream) {
    const float* u_cat = (const float*)d_in[0];
    const float* u_exp = (const float*)d_in[1];
    float* out = (float*)d_out;
    float* photons = out;                                  // (STEPS, NS)
    float* cumt    = out + (size_t)STEPS * NS;             // (STEPS, NS)
    float* hist    = out + 2 * (size_t)STEPS * NS;         // (NBINS+1,)

    char* ws = (char*)d_ws;
    unsigned int*  t1p   = (unsigned int*)(ws + WS_T1P);
    unsigned char* maps  = (unsigned char*)(ws + WS_MAPS);
    unsigned int*  pcnt4 = (unsigned int*)(ws + WS_PCNT4);
    float4*        sums4 = (float4*)(ws + WS_SUMS4);
    unsigned char* enter = (unsigned char*)(ws + WS_ENTER);
    float*         offs  = (float*)(ws + WS_OFFS);
    int*           ptot  = (int*)(ws + WS_PTOT);

    zero_kernel<<<(NBINS + 1 + 255) / 256, 256, 0, stream>>>(hist, ptot);
    map_dwell_kernel<<<NT4 / 256, 256, 0, stream>>>(u_cat, u_exp, t1p, maps, pcnt4, sums4);
    scan_kernel<<<NS / 256, 256, 0, stream>>>(maps, pcnt4, sums4, enter, offs, ptot);
    hist0_kernel<<<1, 64, 0, stream>>>(hist, ptot);
    final_kernel<<<NT4 / 256, 256, 0, stream>>>(u_exp, t1p, enter, offs, photons, cumt, hist);
}